// Round 13
// baseline (247.805 us; speedup 1.0000x reference)
//
#include <hip/hip_runtime.h>
#include <hip/hip_bf16.h>
#include <stdint.h>

// B=16, TH=TS=HS=WS=1024
// res[b,i,o] = sum_j softmax_j(hp[b,i,:].sp[b,j,:]) * hp[b,j,o]
// hp = h*Wh^T + bh ; sp = s*Ws^T + bs
// fp16 operands, f32 MFMA accum.
// R13: GEMM1/2 -> m97-style 128^2 tile, BK=32, 32KB LDS dbuf, <=128 VGPR
// (3-4 blocks/CU TLP hides the 2-phase barrier drain). Conflict-free swizzle
// for 64B rows: byte ^= ((byte>>7)&3)<<4. GEMM3/4 keep 256^2 + XCD swizzle.

typedef _Float16 half_t;
typedef __attribute__((ext_vector_type(8))) _Float16 half8;   // 4 VGPR
typedef __attribute__((ext_vector_type(4))) _Float16 half4;
typedef __attribute__((ext_vector_type(4))) float floatx4;

__device__ __forceinline__ void gl2lds16(const void* g, void* l) {
    __builtin_amdgcn_global_load_lds(
        (const __attribute__((address_space(1))) uint32_t*)(uintptr_t)g,
        (__attribute__((address_space(3))) uint32_t*)(uintptr_t)l,
        16, 0, 0);
}

// ---------------- 128^2 tile GEMM (GEMM1/2): C = A*B^T + bias, fp16 out ----
// A [16384][1024] fp16, B = W [1024][1024] fp16 (row o, K-major). BK=32.
// 4 waves (2x2 of 64x64). LDS tile rows are 64B; swizzle XOR byte bits 4-5
// with (row>>1)&3 -> every aligned 8-lane group of a ds_read_b128 covers all
// eight 16B slots (conflict-free). Applied pre-swizzled on the gl2lds global
// source and folded into the read bases.
template<int WH16T>
__global__ __launch_bounds__(256, 4) void gemm128(
    const half_t* __restrict__ A, const half_t* __restrict__ B,
    const float* __restrict__ bias,
    half_t* __restrict__ Ch, half_t* __restrict__ ChT)
{
    __shared__ char smem[32768];   // [2][ A:8KB | B:8KB ]

    const int tid  = threadIdx.x;
    const int wave = tid >> 6;
    const int lane = tid & 63;
    const int wr = wave >> 1, wc = wave & 1;     // 2x2 waves of 64x64
    const int lr = lane & 15, lg = lane >> 4;

    const int row0 = blockIdx.x * 128;
    const int col0 = blockIdx.y * 128;

    floatx4 acc[4][4];
#pragma unroll
    for (int m = 0; m < 4; ++m)
#pragma unroll
        for (int n = 0; n < 4; ++n)
            acc[m][n] = (floatx4){0.f, 0.f, 0.f, 0.f};

    // stage source offsets (bytes, excl. kk*2), inverse-swizzled:
    long aOff[2], bOff[2];
#pragma unroll
    for (int i = 0; i < 2; ++i) {
        const int off = i * 4096 + tid * 16;           // byte in 8KB operand tile
        const int e = off ^ (((off >> 7) & 3) << 4);   // involution
        const int r = e >> 6, cb = e & 63;             // 64B per row
        aOff[i] = (long)(row0 + r) * 2048 + cb;
        bOff[i] = (long)(col0 + r) * 2048 + cb;
    }
    const int wave_s = __builtin_amdgcn_readfirstlane(wave);

    auto stage = [&](int buf, int kk) {
#pragma unroll
        for (int i = 0; i < 2; ++i)
            gl2lds16((const char*)A + aOff[i] + (long)kk * 2,
                     smem + buf * 16384 + i * 4096 + wave_s * 1024);
#pragma unroll
        for (int i = 0; i < 2; ++i)
            gl2lds16((const char*)B + bOff[i] + (long)kk * 2,
                     smem + buf * 16384 + 8192 + i * 4096 + wave_s * 1024);
    };

    // fragment-read bases (swizzle folded; mt/nt add 1024)
    const uint32_t swx = (uint32_t)((lg * 16) ^ (((lr >> 1) & 3) << 4));
    uint32_t aof = (uint32_t)((wr * 64 + lr) * 64) + swx;
    uint32_t bof = 8192u + (uint32_t)((wc * 64 + lr) * 64) + swx;

    stage(0, 0);
    __syncthreads();

    for (int t = 0; t < 32; ++t) {
        if (t + 1 < 32) stage((t & 1) ^ 1, (t + 1) * 32);

        half8 aF[4], bF[4];
#pragma unroll
        for (int ni = 0; ni < 4; ++ni)
            bF[ni] = *(const half8*)(smem + bof + ni * 1024);
#pragma unroll
        for (int mi = 0; mi < 4; ++mi)
            aF[mi] = *(const half8*)(smem + aof + mi * 1024);
#pragma unroll
        for (int mi = 0; mi < 4; ++mi)
#pragma unroll
            for (int ni = 0; ni < 4; ++ni)
                acc[mi][ni] = __builtin_amdgcn_mfma_f32_16x16x32_f16(
                    aF[mi], bF[ni], acc[mi][ni], 0, 0, 0);

        __syncthreads();
        aof ^= 16384; bof ^= 16384;
    }

    // epilogue: transpose acc through LDS for coalesced 16B stores.
    {
        float* wlds = (float*)(smem + wave * 2304);   // per-wave 16x36 f32
        float bv[4];
#pragma unroll
        for (int n = 0; n < 4; ++n)
            bv[n] = bias[col0 + wc * 64 + n * 16 + lr];
        const int er = lane >> 2, ec = lane & 3;
        const int oc = lane >> 1, tc = lane & 1;
#pragma unroll
        for (int m = 0; m < 4; ++m) {
#pragma unroll
            for (int np = 0; np < 2; ++np) {
#pragma unroll
                for (int n2 = 0; n2 < 2; ++n2)
#pragma unroll
                    for (int j = 0; j < 4; ++j)
                        wlds[(lg * 4 + j) * 36 + n2 * 16 + lr] =
                            acc[m][np * 2 + n2][j] + bv[np * 2 + n2];
                const int grow = row0 + wr * 64 + m * 16;
                const int gcol = col0 + wc * 64 + np * 32;
                float4 q0 = *(float4*)&wlds[er * 36 + ec * 8];
                float4 q1 = *(float4*)&wlds[er * 36 + ec * 8 + 4];
                {
                    half8 o = { (half_t)q0.x, (half_t)q0.y, (half_t)q0.z, (half_t)q0.w,
                                (half_t)q1.x, (half_t)q1.y, (half_t)q1.z, (half_t)q1.w };
                    *(half8*)&Ch[(long)(grow + er) * 1024 + gcol + ec * 8] = o;
                }
                if (WH16T) {
                    float tv[8];
#pragma unroll
                    for (int k = 0; k < 8; ++k)
                        tv[k] = wlds[(tc * 8 + k) * 36 + oc];
                    half8 o = { (half_t)tv[0], (half_t)tv[1], (half_t)tv[2], (half_t)tv[3],
                                (half_t)tv[4], (half_t)tv[5], (half_t)tv[6], (half_t)tv[7] };
                    const int gt = grow + tc * 8;
                    *(half8*)&ChT[(long)(gt >> 10) * 1048576
                                  + (long)(gcol + oc) * 1024 + (gt & 1023)] = o;
                }
                __builtin_amdgcn_s_waitcnt(0);
            }
        }
    }
}

// ---------------- 256^2 tile GEMM (GEMM3/4), XCD-batch swizzle -------------
#define NT16 16   // K = 1024, BK = 64

template<int SWZ>
__global__ __launch_bounds__(512, 2) void gemm256(
    const half_t* __restrict__ A, const half_t* __restrict__ B,
    float* __restrict__ Cf,
    int lda, int ldb,
    long aBatch, long bBatch, long cfBatch, int ldcf)
{
    extern __shared__ char smem[];   // [2][ A:32KB | B:32KB ] = 128KB

    const int tid  = threadIdx.x;
    const int wave = tid >> 6;
    const int lane = tid & 63;
    const int wr = wave >> 2;
    const int wc = wave & 3;
    const int lr = lane & 15, lg = lane >> 4;

    long batch; int row0, col0;
    if constexpr (SWZ) {
        const int lin = blockIdx.x + (blockIdx.y << 2) + (blockIdx.z << 4);
        const int xcd = lin & 7, per = lin >> 3;
        batch = (xcd << 1) | (per >> 4);
        const int wt = per & 15;
        row0 = (wt & 3) * 256;
        col0 = (wt >> 2) * 256;
    } else {
        batch = blockIdx.z;
        row0 = blockIdx.x * 256;
        col0 = blockIdx.y * 256;
    }

    const half_t* Ab = A + batch * aBatch;
    const half_t* Bb = B + batch * bBatch;

    floatx4 acc[8][4];
#pragma unroll
    for (int m = 0; m < 8; ++m)
#pragma unroll
        for (int n = 0; n < 4; ++n)
            acc[m][n] = (floatx4){0.f, 0.f, 0.f, 0.f};

    long aOff[2][2], bOff[2][2];
#pragma unroll
    for (int hh = 0; hh < 2; ++hh)
#pragma unroll
        for (int i = 0; i < 2; ++i) {
            const int off = hh * 16384 + i * 8192 + tid * 16;
            const int e = off ^ (((off >> 7) & 7) << 4);
            const int r = e >> 7, cb = e & 127;
            aOff[hh][i] = (long)(row0 + r) * (long)(lda * 2) + cb;
            bOff[hh][i] = (long)(col0 + r) * (long)(ldb * 2) + cb;
        }

    const int wave_s = __builtin_amdgcn_readfirstlane(wave);
    auto stage = [&](int buf, int kk) {
#pragma unroll
        for (int hh = 0; hh < 2; ++hh)
#pragma unroll
            for (int i = 0; i < 2; ++i)
                gl2lds16((const char*)Ab + aOff[hh][i] + (long)kk * 2,
                         smem + buf * 65536 + hh * 16384 + i * 8192 + wave_s * 1024);
#pragma unroll
        for (int hh = 0; hh < 2; ++hh)
#pragma unroll
            for (int i = 0; i < 2; ++i)
                gl2lds16((const char*)Bb + bOff[hh][i] + (long)kk * 2,
                         smem + buf * 65536 + 32768 + hh * 16384 + i * 8192 + wave_s * 1024);
    };

    uint32_t aof0 = (uint32_t)((wr * 128 + lr) * 128 + ((lg * 16) ^ ((lr & 7) << 4)));
    uint32_t aof1 = (uint32_t)((wr * 128 + lr) * 128 + ((64 + lg * 16) ^ ((lr & 7) << 4)));
    uint32_t bof0 = (uint32_t)(32768 + (wc * 64 + lr) * 128 + ((lg * 16) ^ ((lr & 7) << 4)));
    uint32_t bof1 = (uint32_t)(32768 + (wc * 64 + lr) * 128 + ((64 + lg * 16) ^ ((lr & 7) << 4)));

    stage(0, 0);
    __syncthreads();

    for (int t = 0; t < NT16; ++t) {
        if (t + 1 < NT16) stage((t & 1) ^ 1, (t + 1) * 64);

        half8 aF[4][2], bF[4][2];
#pragma unroll
        for (int ni = 0; ni < 4; ++ni) {
            bF[ni][0] = *(const half8*)(smem + bof0 + ni * 2048);
            bF[ni][1] = *(const half8*)(smem + bof1 + ni * 2048);
        }
#pragma unroll
        for (int mi = 0; mi < 4; ++mi) {
            aF[mi][0] = *(const half8*)(smem + aof0 + mi * 2048);
            aF[mi][1] = *(const half8*)(smem + aof1 + mi * 2048);
        }
#pragma unroll
        for (int mi = 0; mi < 4; ++mi)
#pragma unroll
            for (int ni = 0; ni < 4; ++ni)
#pragma unroll
                for (int ks = 0; ks < 2; ++ks)
                    acc[mi][ni] = __builtin_amdgcn_mfma_f32_16x16x32_f16(
                        aF[mi][ks], bF[ni][ks], acc[mi][ni], 0, 0, 0);
#pragma unroll
        for (int mi = 0; mi < 4; ++mi) {
            aF[mi][0] = *(const half8*)(smem + aof0 + (4 + mi) * 2048);
            aF[mi][1] = *(const half8*)(smem + aof1 + (4 + mi) * 2048);
        }
#pragma unroll
        for (int mi = 0; mi < 4; ++mi)
#pragma unroll
            for (int ni = 0; ni < 4; ++ni)
#pragma unroll
                for (int ks = 0; ks < 2; ++ks)
                    acc[4 + mi][ni] = __builtin_amdgcn_mfma_f32_16x16x32_f16(
                        aF[mi][ks], bF[ni][ks], acc[4 + mi][ni], 0, 0, 0);

        __syncthreads();
        aof0 ^= 65536; aof1 ^= 65536; bof0 ^= 65536; bof1 ^= 65536;
    }

    // epilogue: transpose acc through LDS for coalesced f32x4 stores.
    {
        float* wlds = (float*)(smem + wave * 2304);
        const int er = lane >> 2, ec = lane & 3;
#pragma unroll
        for (int m = 0; m < 8; ++m) {
#pragma unroll
            for (int np = 0; np < 2; ++np) {
#pragma unroll
                for (int n2 = 0; n2 < 2; ++n2)
#pragma unroll
                    for (int j = 0; j < 4; ++j)
                        wlds[(lg * 4 + j) * 36 + n2 * 16 + lr] = acc[m][np * 2 + n2][j];
                const int grow = row0 + wr * 128 + m * 16;
                const int gcol = col0 + wc * 64 + np * 32;
                float4 q0 = *(float4*)&wlds[er * 36 + ec * 8];
                float4 q1 = *(float4*)&wlds[er * 36 + ec * 8 + 4];
                float* p = Cf + batch * cfBatch + (long)(grow + er) * ldcf + gcol + ec * 8;
                *(float4*)p = q0;
                *(float4*)(p + 4) = q1;
                __builtin_amdgcn_s_waitcnt(0);
            }
        }
    }
}

// In-place: reads f32 row (1024), writes fp16 probabilities over its own first half.
__global__ void softmax_inplace(float* __restrict__ S) {
    const long r = blockIdx.x;
    float* row = S + r * 1024;
    const int tid = threadIdx.x;
    const int wave = tid >> 6, lane = tid & 63;

    float4 v = ((const float4*)row)[tid];
    float mx = fmaxf(fmaxf(v.x, v.y), fmaxf(v.z, v.w));
#pragma unroll
    for (int off = 32; off > 0; off >>= 1)
        mx = fmaxf(mx, __shfl_xor(mx, off));
    __shared__ float rmx[4], rsm[4];
    if (lane == 0) rmx[wave] = mx;
    __syncthreads();
    mx = fmaxf(fmaxf(rmx[0], rmx[1]), fmaxf(rmx[2], rmx[3]));

    float e0 = __expf(v.x - mx), e1 = __expf(v.y - mx);
    float e2 = __expf(v.z - mx), e3 = __expf(v.w - mx);
    float s = e0 + e1 + e2 + e3;
#pragma unroll
    for (int off = 32; off > 0; off >>= 1)
        s += __shfl_xor(s, off);
    if (lane == 0) rsm[wave] = s;
    __syncthreads();
    s = rsm[0] + rsm[1] + rsm[2] + rsm[3];

    const float inv = 1.0f / s;
    half4 o = { (half_t)(e0 * inv), (half_t)(e1 * inv), (half_t)(e2 * inv), (half_t)(e3 * inv) };
    ((half4*)((half_t*)S + r * 2048))[tid] = o;
}

__global__ void cvt_f16(const float4* __restrict__ src, half4* __restrict__ dst, int n4) {
    const int stride = gridDim.x * blockDim.x;
    for (int i = blockIdx.x * blockDim.x + threadIdx.x; i < n4; i += stride) {
        float4 v = src[i];
        half4 o = { (half_t)v.x, (half_t)v.y, (half_t)v.z, (half_t)v.w };
        dst[i] = o;
    }
}

extern "C" void kernel_launch(void* const* d_in, const int* in_sizes, int n_in,
                              void* d_out, int out_size, void* d_ws, size_t ws_size,
                              hipStream_t stream) {
    const float* h  = (const float*)d_in[0];
    const float* s  = (const float*)d_in[1];
    const float* Wh = (const float*)d_in[2];
    const float* bh = (const float*)d_in[3];
    const float* Ws = (const float*)d_in[4];
    const float* bs = (const float*)d_in[5];

    const long MB = 16384;   // B*TH
    const long D  = 1024;

    // workspace carve (~228 MB)
    char* w = (char*)d_ws;
    float*  sc   = (float*)w;   w += MB * D * 4;   // 64MB scores (fp16 probs in place)
    half_t* Wh16 = (half_t*)w;  w += D * D * 2;
    half_t* Ws16 = (half_t*)w;  w += D * D * 2;
    half_t* h16  = (half_t*)w;  w += MB * D * 2;
    half_t* s16  = (half_t*)w;  w += MB * D * 2;
    half_t* hp16 = (half_t*)w;  w += MB * D * 2;
    half_t* sp16 = (half_t*)w;  w += MB * D * 2;
    half_t* hpT  = (half_t*)w;  w += MB * D * 2;   // [16][o][t]

    (void)hipFuncSetAttribute(reinterpret_cast<const void*>(&gemm256<1>),
                        hipFuncAttributeMaxDynamicSharedMemorySize, 131072);

    cvt_f16<<<512,  256, 0, stream>>>((const float4*)Wh, (half4*)Wh16, (int)(D * D / 4));
    cvt_f16<<<512,  256, 0, stream>>>((const float4*)Ws, (half4*)Ws16, (int)(D * D / 4));
    cvt_f16<<<2048, 256, 0, stream>>>((const float4*)h,  (half4*)h16,  (int)(MB * D / 4));
    cvt_f16<<<2048, 256, 0, stream>>>((const float4*)s,  (half4*)s16,  (int)(MB * D / 4));

    // GEMM1: hp = h*Wh^T + bh (fp16 out + per-batch transposed copy)
    gemm128<1><<<dim3(128, 8), 256, 0, stream>>>(h16, Wh16, bh, hp16, hpT);
    // GEMM2: sp = s*Ws^T + bs
    gemm128<0><<<dim3(128, 8), 256, 0, stream>>>(s16, Ws16, bs, sp16, nullptr);
    // GEMM3: scores[b] = hp_b * sp_b^T (f32), XCD-batch swizzle
    gemm256<1><<<dim3(4, 4, 16), 512, 131072, stream>>>(
        hp16, sp16, sc, 1024, 1024, 1048576L, 1048576L, 1048576L, 1024);
    // softmax over j, fp16 probs in place (row stride 2048 halves)
    softmax_inplace<<<16384, 256, 0, stream>>>(sc);
    // GEMM4: out[b] = probs_b * hpT_b^T (f32 -> d_out), XCD-batch swizzle
    gemm256<1><<<dim3(4, 4, 16), 512, 131072, stream>>>(
        (const half_t*)sc, hpT, (float*)d_out, 2048, 1024,
        2097152L, 1048576L, 1048576L, 1024);
}